// Round 5
// baseline (17848.744 us; speedup 1.0000x reference)
//
#include <hip/hip_runtime.h>
#include <stdint.h>

#define T_STEPS 4096
#define IN_DIM  1024
#define H_DIM   2048
#define OUT_DIM 512
#define W_STRIDE 3072        // IN + H
#define NBLK    256          // one persistent block per CU
#define NTHR    512          // 8 waves/block -> VGPR cap 256
#define POLL_GUARD 65536     // ~20 ms of spinning before declaring wedge
#define NREP    8            // h-packet replicas (contention reduction)

typedef __attribute__((ext_vector_type(4))) float floatx4;

// XOR swizzle on 16B granules: keeps float4 alignment, spreads bank groups.
__device__ __forceinline__ int swz(int q) { return q ^ ((q >> 3) & 7); }

// Fast transcendentals for the serial [K] chain (one wave, critical path to
// the h publish). rcp is ~1 ulp; overflow-safe forms (no inf*0).
__device__ __forceinline__ float fsigmoid(float v) {
  return __builtin_amdgcn_rcpf(1.f + __expf(-v));
}
__device__ __forceinline__ float ftanh(float v) {
  return 1.f - 2.f * __builtin_amdgcn_rcpf(1.f + __expf(2.f * v));
}

// ---------------------------------------------------------------------------
// Persistent fused LSTM scan. Block b owns h rows [8b, 8b+8).
// 512 threads: grp = tid>>7 = gate; u = tid&127 = col-slice (24 cols).
// Thread holds W_gate[row0+r][24u..24u+24) for r<8: 192 fp32 register-resident.
//
// Single-hop dataflow handshake (measured: 29.1ms -> 17.8ms): each h value is
// published as ONE aligned 8B packet (tag<<32 | float_bits) via relaxed
// agent-scope atomic store; consumers poll, tag>=t means valid.
//
// R9 change: 8x REPLICATED publish. All 256 blocks polling one 16KB region
// made ~256 readers per cache line per step at the coherent point; the
// queueing there is the theory for the ~8k-cycle step overhead. Producer now
// fire-and-forget stores each packet to NREP replicas (no drain, concurrent
// in flight); consumer b polls only replica (b & rep_mask) -> per-line
// readers drop 8x. Safety is replica-invariant: p overwrites a buffer only
// after every k published tag>=t in p's replica, and k's publish (to ALL
// replicas, after its poll loads returned) implies k finished reading the
// buffer p overwrites. memset(0) == valid (h0=0, tag0) state everywhere.
// ---------------------------------------------------------------------------
#define WDECL(r) floatx4 w##r##_0, w##r##_1, w##r##_2, w##r##_3, w##r##_4, w##r##_5
#define WLOAD(r) do { const float* rp_ = wbase + (size_t)(r) * W_STRIDE;      \
    w##r##_0 = *(const floatx4*)(rp_ +  0);                                   \
    w##r##_1 = *(const floatx4*)(rp_ +  4);                                   \
    w##r##_2 = *(const floatx4*)(rp_ +  8);                                   \
    w##r##_3 = *(const floatx4*)(rp_ + 12);                                   \
    w##r##_4 = *(const floatx4*)(rp_ + 16);                                   \
    w##r##_5 = *(const floatx4*)(rp_ + 20); } while (0)
#define FMA4(acc, wq) do {                                                    \
    acc = fmaf(wq.x, v.x, acc); acc = fmaf(wq.y, v.y, acc);                   \
    acc = fmaf(wq.z, v.z, acc); acc = fmaf(wq.w, v.w, acc); } while (0)
#define FMAJ(j) do { v = *(const floatx4*)(xh + a_v##j);                      \
    FMA4(ac0, w0_##j); FMA4(ac1, w1_##j); FMA4(ac2, w2_##j);                  \
    FMA4(ac3, w3_##j); FMA4(ac4, w4_##j); FMA4(ac5, w5_##j);                  \
    FMA4(ac6, w6_##j); FMA4(ac7, w7_##j); } while (0)
#define WRED(acc, r) do { float a_ = acc;                                     \
    a_ += __shfl_down(a_, 32, 64); a_ += __shfl_down(a_, 16, 64);             \
    a_ += __shfl_down(a_, 8, 64);  a_ += __shfl_down(a_, 4, 64);              \
    a_ += __shfl_down(a_, 2, 64);  a_ += __shfl_down(a_, 1, 64);              \
    if (lane == 0) red[wv * 8 + (r)] = a_; } while (0)

__global__ __launch_bounds__(NTHR, 2)
void lstm_scan(const float* __restrict__ Wi, const float* __restrict__ Wf,
               const float* __restrict__ Wo, const float* __restrict__ Wc,
               const float* __restrict__ bi, const float* __restrict__ bff,
               const float* __restrict__ bo, const float* __restrict__ bc,
               const float* __restrict__ x,
               unsigned long long* __restrict__ hcomm,  // [NREP][2][H_DIM]
               float* __restrict__ hbuf,                // [H_DIM] final h
               float* __restrict__ cbuf,                // [H_DIM] final c
               int rep_mask)                            // 7 normally, 0 fallback
{
  __shared__ float xh[768 * 4];   // concat(x,h) in XOR-swizzled 16B granules
  __shared__ float red[8 * 8];    // per-wave partials (8 waves x 8 rows)
  __shared__ float bl[32];        // biases (gate*8+row)
  __shared__ float cl[8];         // cell state for this block's rows

  const int tid  = threadIdx.x;
  const int b    = blockIdx.x;
  const int row0 = b << 3;
  const int grp  = tid >> 7;      // gate id 0..3
  const int u    = tid & 127;     // column slice: cols [24u, 24u+24)
  const int wv   = tid >> 6;      // wave id 0..7
  const int lane = tid & 63;

  const float* Wsel = (grp == 0) ? Wi : (grp == 1) ? Wf : (grp == 2) ? Wo : Wc;
  const float* wbase = Wsel + (size_t)row0 * W_STRIDE + 24 * u;

  WDECL(0); WDECL(1); WDECL(2); WDECL(3);
  WDECL(4); WDECL(5); WDECL(6); WDECL(7);
  WLOAD(0); WLOAD(1); WLOAD(2); WLOAD(3);
  WLOAD(4); WLOAD(5); WLOAD(6); WLOAD(7);

  if (tid < 32) {
    const float* Bsel = (tid < 8) ? bi : (tid < 16) ? bff : (tid < 24) ? bo : bc;
    bl[tid] = Bsel[row0 + (tid & 7)];
  }
  if (tid < 8) cl[tid] = 0.f;
  __syncthreads();

  // this block's poll replica (u64 offset; replica stride = 2*H_DIM = 1<<12)
  unsigned long long* const myrep = hcomm + ((size_t)(b & rep_mask) << 12);

  // loop-invariant LDS addresses (dword units)
  const int a_v0 = swz(6 * u + 0) << 2;
  const int a_v1 = swz(6 * u + 1) << 2;
  const int a_v2 = swz(6 * u + 2) << 2;
  const int a_v3 = swz(6 * u + 3) << 2;
  const int a_v4 = swz(6 * u + 4) << 2;
  const int a_v5 = swz(6 * u + 5) << 2;
  const int hw0 = (swz(256 + (tid >> 2) +   0) << 2) + (tid & 3);
  const int hw1 = (swz(256 + (tid >> 2) + 128) << 2) + (tid & 3);
  const int hw2 = (swz(256 + (tid >> 2) + 256) << 2) + (tid & 3);
  const int hw3 = (swz(256 + (tid >> 2) + 384) << 2) + (tid & 3);

  float hlast = 0.f;
  int   alive = 1;   // cleared if a poll ever exhausts POLL_GUARD

  for (int t = 0; t < T_STEPS; ++t) {
    // [A] stage x[t] (granules 0..255); issue early so the global load
    // latency hides under the h poll below.
    if (tid >= 256) {
      const int q = tid - 256;
      const floatx4 xv = *(const floatx4*)(x + ((size_t)t << 10) + (q << 2));
      *(floatx4*)(xh + (swz(q) << 2)) = xv;
    }

    // [B+D fused] poll the 4 h packets this thread stages, from this block's
    // replica only. tag>=t implies the float in the same 8B is valid.
    {
      unsigned long long* hb = myrep + ((size_t)(t & 1) << 11);
      const unsigned tt = (unsigned)t;
      float h0 = 0.f, h1 = 0.f, h2 = 0.f, h3 = 0.f;
      bool d0 = false, d1 = false, d2 = false, d3 = false;
      int guard = 0;
      while (alive) {
        unsigned long long pv;
        if (!d0) {
          pv = __hip_atomic_load(&hb[tid], __ATOMIC_RELAXED,
                                 __HIP_MEMORY_SCOPE_AGENT);
          if ((unsigned)(pv >> 32) >= tt) { h0 = __uint_as_float((unsigned)pv); d0 = true; }
        }
        if (!d1) {
          pv = __hip_atomic_load(&hb[tid + 512], __ATOMIC_RELAXED,
                                 __HIP_MEMORY_SCOPE_AGENT);
          if ((unsigned)(pv >> 32) >= tt) { h1 = __uint_as_float((unsigned)pv); d1 = true; }
        }
        if (!d2) {
          pv = __hip_atomic_load(&hb[tid + 1024], __ATOMIC_RELAXED,
                                 __HIP_MEMORY_SCOPE_AGENT);
          if ((unsigned)(pv >> 32) >= tt) { h2 = __uint_as_float((unsigned)pv); d2 = true; }
        }
        if (!d3) {
          pv = __hip_atomic_load(&hb[tid + 1536], __ATOMIC_RELAXED,
                                 __HIP_MEMORY_SCOPE_AGENT);
          if ((unsigned)(pv >> 32) >= tt) { h3 = __uint_as_float((unsigned)pv); d3 = true; }
        }
        if (d0 & d1 & d2 & d3) break;
        if (++guard > POLL_GUARD) { alive = 0; break; }  // wedge -> bail loud
        __builtin_amdgcn_s_sleep(1);
      }
      xh[hw0] = h0;
      xh[hw1] = h1;
      xh[hw2] = h2;
      xh[hw3] = h3;
    }
    __syncthreads();   // sync1: xh fully staged (x + h)

    // [F] 192 FMAs against register-resident weights
    float ac0 = 0.f, ac1 = 0.f, ac2 = 0.f, ac3 = 0.f,
          ac4 = 0.f, ac5 = 0.f, ac6 = 0.f, ac7 = 0.f;
    {
      floatx4 v;
      FMAJ(0); FMAJ(1); FMAJ(2); FMAJ(3); FMAJ(4); FMAJ(5);
    }

    // [G] wave reduction (64 lanes -> lane 0) for the 8 row-sums
    WRED(ac0, 0); WRED(ac1, 1); WRED(ac2, 2); WRED(ac3, 3);
    WRED(ac4, 4); WRED(ac5, 5); WRED(ac6, 6); WRED(ac7, 7);
    __syncthreads();   // sync2: partials visible (also fences xh reuse)

    // [K] combine partials + gates + state update (rows by threads 0..7),
    // then publish packet (tag t+1, h) to all replicas -- fire-and-forget
    // relaxed stores, concurrently in flight, no drain needed.
    if (tid < 8) {
      const int rr = tid;
      const float pi = bl[rr]      + red[0 * 8 + rr] + red[1 * 8 + rr];
      const float pf = bl[8 + rr]  + red[2 * 8 + rr] + red[3 * 8 + rr];
      const float po = bl[16 + rr] + red[4 * 8 + rr] + red[5 * 8 + rr];
      const float pc = bl[24 + rr] + red[6 * 8 + rr] + red[7 * 8 + rr];
      const float iv = fsigmoid(pi);
      const float fv = fsigmoid(pf);
      const float ov = fsigmoid(po);
      const float ct = ftanh(pc);
      const float cn = fv * cl[rr] + iv * ct;
      cl[rr] = cn;
      const float hv = ov * ftanh(cn);
      hlast = hv;
      const unsigned long long pk =
          ((unsigned long long)(unsigned)(t + 1) << 32) |
          (unsigned long long)__float_as_uint(hv);
      unsigned long long* pb =
          hcomm + (((size_t)((t + 1) & 1)) << 11) + row0 + rr;
      for (int r = 0; r <= rep_mask; ++r)
        __hip_atomic_store(pb + ((size_t)r << 12), pk, __ATOMIC_RELAXED,
                           __HIP_MEMORY_SCOPE_AGENT);
    }
    // no barrier here: next iteration's xh writes are behind sync1, and
    // red[] rewrites are behind next sync1 as well (wave 0 reaches it only
    // after [K]).
  }

  if (tid < 8) {
    hbuf[row0 + tid] = hlast;
    cbuf[row0 + tid] = cl[tid];
  }
}

// ---------------------------------------------------------------------------
// out[0:512] = W2 @ [h; c] + b2   (fp32 in, fp32 out)
// ---------------------------------------------------------------------------
__global__ __launch_bounds__(256)
void final_kernel(const float* __restrict__ W2, const float* __restrict__ b2,
                  const float* __restrict__ hfin, const float* __restrict__ cfin,
                  float* __restrict__ out)
{
  const int wv   = threadIdx.x >> 6;
  const int lane = threadIdx.x & 63;
  const int row  = (blockIdx.x << 2) + wv;
  const float* wr = W2 + (size_t)row * (2 * H_DIM);
  float acc = 0.f;
#pragma unroll 4
  for (int k = lane; k < H_DIM; k += 64) {
    acc = fmaf(wr[k], hfin[k], acc);
    acc = fmaf(wr[H_DIM + k], cfin[k], acc);
  }
#pragma unroll
  for (int off = 32; off > 0; off >>= 1) acc += __shfl_down(acc, off, 64);
  if (lane == 0) out[row] = acc + b2[row];
}

__global__ __launch_bounds__(256)
void copy_h_kernel(const float* __restrict__ hfin, float* __restrict__ out)
{
  const int i = blockIdx.x * 256 + threadIdx.x;
  if (i < H_DIM) out[OUT_DIM + i] = hfin[i];
}

// ---------------------------------------------------------------------------
extern "C" void kernel_launch(void* const* d_in, const int* in_sizes, int n_in,
                              void* d_out, int out_size, void* d_ws, size_t ws_size,
                              hipStream_t stream)
{
  const float* x   = (const float*)d_in[0];
  const float* Wi  = (const float*)d_in[1];
  const float* bi  = (const float*)d_in[2];
  const float* Wf  = (const float*)d_in[3];
  const float* bff = (const float*)d_in[4];
  const float* Wo  = (const float*)d_in[5];
  const float* bo  = (const float*)d_in[6];
  const float* Wc  = (const float*)d_in[7];
  const float* bc  = (const float*)d_in[8];
  const float* W2  = (const float*)d_in[9];
  const float* b2  = (const float*)d_in[10];
  float* out = (float*)d_out;

  // workspace: [hcomm NREP*2*H u64 = 256 KB][hbuf H f32][cbuf H f32]
  const size_t rep_full = (size_t)NREP * 2 * H_DIM * sizeof(unsigned long long);
  const size_t tail     = (size_t)2 * H_DIM * sizeof(float);
  int    rep_mask  = NREP - 1;
  size_t rep_bytes = rep_full;
  if (ws_size < rep_full + tail) {           // fallback: single replica (~48 KB)
    rep_mask  = 0;
    rep_bytes = (size_t)2 * H_DIM * sizeof(unsigned long long);
  }

  char* ws = (char*)d_ws;
  unsigned long long* hcomm = (unsigned long long*)ws;
  float* hbuf = (float*)(ws + rep_bytes);
  float* cbuf = hbuf + H_DIM;

  // zeroed packets == (tag 0, h=0): the valid initial state for step 0
  hipMemsetAsync(hcomm, 0, rep_bytes, stream);

  lstm_scan<<<dim3(NBLK), dim3(NTHR), 0, stream>>>(
      Wi, Wf, Wo, Wc, bi, bff, bo, bc, x, hcomm, hbuf, cbuf, rep_mask);
  final_kernel<<<dim3(OUT_DIM / 4), 256, 0, stream>>>(W2, b2, hbuf, cbuf, out);
  copy_h_kernel<<<dim3((H_DIM + 255) / 256), 256, 0, stream>>>(hbuf, out);
}

// Round 8
// 17584.605 us; speedup vs baseline: 1.0150x; 1.0150x over previous
//
#include <hip/hip_runtime.h>
#include <stdint.h>

#define T_STEPS 4096
#define IN_DIM  1024
#define H_DIM   2048
#define OUT_DIM 512
#define W_STRIDE 3072        // IN + H
#define NBLK    256          // one persistent block per CU
#define NTHR    512          // 8 waves/block -> VGPR cap 256 (2 waves/SIMD)
#define POLL_GUARD 65536     // ~20 ms of spinning before declaring wedge

typedef __attribute__((ext_vector_type(4))) float floatx4;

// XOR swizzle on 16B granules: keeps float4 alignment, spreads bank groups.
__device__ __forceinline__ int swz(int q) { return q ^ ((q >> 3) & 7); }

// Fast transcendentals for the serial [K] chain (one wave, critical path to
// the h publish). rcp is ~1 ulp; overflow-safe forms (no inf*0).
__device__ __forceinline__ float fsigmoid(float v) {
  return __builtin_amdgcn_rcpf(1.f + __expf(-v));
}
__device__ __forceinline__ float ftanh(float v) {
  return 1.f - 2.f * __builtin_amdgcn_rcpf(1.f + __expf(2.f * v));
}

// ---------------------------------------------------------------------------
// Persistent fused LSTM scan. Block b owns h rows [8b, 8b+8).
// 512 threads: grp = tid>>7 = gate; u = tid&127 = col-slice (24 cols).
// Thread holds W_gate[row0+r][24u..24u+24) for r<8: 192 fp32.
//
// R10 change: FORCE weight register residency. rocprof showed VGPR_Count=128
// with a 192-float/thread weight slice -> the allocator was rematerializing
// weights as per-step global loads: 100 MB/step streamed from MALL, which at
// the measured 4.35us/step is ~23 TB/s = MALL BW ceiling. That, not the
// handshake, is the theory for the current floor (R9's 8x-replication null
// killed the contention theory). The WPIN opaque-asm below makes each loaded
// weight vector the result of a volatile asm -> cannot be remat'ed as a
// load; allocator must keep 192 VGPRs live (cap 256 at launch_bounds(512,2),
// occupancy unaffected: only 1 block/CU resident anyway).
// Verification tell: VGPR_Count must jump to >=240.
//
// Handshake (measured 29.1->17.8ms): single-hop 8B (tag<<32|float) packet,
// relaxed agent-scope store; consumers poll tag>=t. Ping-pong on t&1.
// Bounded bailout so any stale-state replay surfaces as a wrong answer, not
// a hung container. 8x replication removed (measured null, R9).
// ---------------------------------------------------------------------------
#define WDECL(r) floatx4 w##r##_0, w##r##_1, w##r##_2, w##r##_3, w##r##_4, w##r##_5
#define WLOAD(r) do { const float* rp_ = wbase + (size_t)(r) * W_STRIDE;      \
    w##r##_0 = *(const floatx4*)(rp_ +  0);                                   \
    w##r##_1 = *(const floatx4*)(rp_ +  4);                                   \
    w##r##_2 = *(const floatx4*)(rp_ +  8);                                   \
    w##r##_3 = *(const floatx4*)(rp_ + 12);                                   \
    w##r##_4 = *(const floatx4*)(rp_ + 16);                                   \
    w##r##_5 = *(const floatx4*)(rp_ + 20); } while (0)
// Opaque pin: weights become volatile-asm results -> no remat, must stay in
// VGPRs across the whole scan loop.
#define WPIN(r) asm volatile("" : "+v"(w##r##_0), "+v"(w##r##_1),             \
    "+v"(w##r##_2), "+v"(w##r##_3), "+v"(w##r##_4), "+v"(w##r##_5))
#define FMA4(acc, wq) do {                                                    \
    acc = fmaf(wq.x, v.x, acc); acc = fmaf(wq.y, v.y, acc);                   \
    acc = fmaf(wq.z, v.z, acc); acc = fmaf(wq.w, v.w, acc); } while (0)
#define FMAJ(j) do { v = *(const floatx4*)(xh + a_v##j);                      \
    FMA4(ac0, w0_##j); FMA4(ac1, w1_##j); FMA4(ac2, w2_##j);                  \
    FMA4(ac3, w3_##j); FMA4(ac4, w4_##j); FMA4(ac5, w5_##j);                  \
    FMA4(ac6, w6_##j); FMA4(ac7, w7_##j); } while (0)
#define WRED(acc, r) do { float a_ = acc;                                     \
    a_ += __shfl_down(a_, 32, 64); a_ += __shfl_down(a_, 16, 64);             \
    a_ += __shfl_down(a_, 8, 64);  a_ += __shfl_down(a_, 4, 64);              \
    a_ += __shfl_down(a_, 2, 64);  a_ += __shfl_down(a_, 1, 64);              \
    if (lane == 0) red[wv * 8 + (r)] = a_; } while (0)

__global__ __launch_bounds__(NTHR, 2)
void lstm_scan(const float* __restrict__ Wi, const float* __restrict__ Wf,
               const float* __restrict__ Wo, const float* __restrict__ Wc,
               const float* __restrict__ bi, const float* __restrict__ bff,
               const float* __restrict__ bo, const float* __restrict__ bc,
               const float* __restrict__ x,
               unsigned long long* __restrict__ hcomm,  // [2][H_DIM] packets
               float* __restrict__ hbuf,                // [H_DIM] final h
               float* __restrict__ cbuf)                // [H_DIM] final c
{
  __shared__ float xh[768 * 4];   // concat(x,h) in XOR-swizzled 16B granules
  __shared__ float red[8 * 8];    // per-wave partials (8 waves x 8 rows)
  __shared__ float bl[32];        // biases (gate*8+row)
  __shared__ float cl[8];         // cell state for this block's rows

  const int tid  = threadIdx.x;
  const int b    = blockIdx.x;
  const int row0 = b << 3;
  const int grp  = tid >> 7;      // gate id 0..3
  const int u    = tid & 127;     // column slice: cols [24u, 24u+24)
  const int wv   = tid >> 6;      // wave id 0..7
  const int lane = tid & 63;

  const float* Wsel = (grp == 0) ? Wi : (grp == 1) ? Wf : (grp == 2) ? Wo : Wc;
  const float* wbase = Wsel + (size_t)row0 * W_STRIDE + 24 * u;

  WDECL(0); WDECL(1); WDECL(2); WDECL(3);
  WDECL(4); WDECL(5); WDECL(6); WDECL(7);
  WLOAD(0); WLOAD(1); WLOAD(2); WLOAD(3);
  WLOAD(4); WLOAD(5); WLOAD(6); WLOAD(7);
  WPIN(0); WPIN(1); WPIN(2); WPIN(3);
  WPIN(4); WPIN(5); WPIN(6); WPIN(7);

  if (tid < 32) {
    const float* Bsel = (tid < 8) ? bi : (tid < 16) ? bff : (tid < 24) ? bo : bc;
    bl[tid] = Bsel[row0 + (tid & 7)];
  }
  if (tid < 8) cl[tid] = 0.f;
  __syncthreads();

  // loop-invariant LDS addresses (dword units)
  const int a_v0 = swz(6 * u + 0) << 2;
  const int a_v1 = swz(6 * u + 1) << 2;
  const int a_v2 = swz(6 * u + 2) << 2;
  const int a_v3 = swz(6 * u + 3) << 2;
  const int a_v4 = swz(6 * u + 4) << 2;
  const int a_v5 = swz(6 * u + 5) << 2;
  const int hw0 = (swz(256 + (tid >> 2) +   0) << 2) + (tid & 3);
  const int hw1 = (swz(256 + (tid >> 2) + 128) << 2) + (tid & 3);
  const int hw2 = (swz(256 + (tid >> 2) + 256) << 2) + (tid & 3);
  const int hw3 = (swz(256 + (tid >> 2) + 384) << 2) + (tid & 3);

  float hlast = 0.f;
  int   alive = 1;   // cleared if a poll ever exhausts POLL_GUARD

  for (int t = 0; t < T_STEPS; ++t) {
    // [A] stage x[t] (granules 0..255); issue early so the global load
    // latency hides under the h poll below.
    if (tid >= 256) {
      const int q = tid - 256;
      const floatx4 xv = *(const floatx4*)(x + ((size_t)t << 10) + (q << 2));
      *(floatx4*)(xh + (swz(q) << 2)) = xv;
    }

    // [B+D fused] poll the 4 h packets this thread stages. tag>=t implies
    // the float in the same 8B is this step's value (atomicity of aligned
    // 8B stores). Guarded re-polls: only laggard slots re-issue loads.
    {
      unsigned long long* hb = hcomm + ((size_t)(t & 1) << 11);
      const unsigned tt = (unsigned)t;
      float h0 = 0.f, h1 = 0.f, h2 = 0.f, h3 = 0.f;
      bool d0 = false, d1 = false, d2 = false, d3 = false;
      int guard = 0;
      while (alive) {
        unsigned long long pv;
        if (!d0) {
          pv = __hip_atomic_load(&hb[tid], __ATOMIC_RELAXED,
                                 __HIP_MEMORY_SCOPE_AGENT);
          if ((unsigned)(pv >> 32) >= tt) { h0 = __uint_as_float((unsigned)pv); d0 = true; }
        }
        if (!d1) {
          pv = __hip_atomic_load(&hb[tid + 512], __ATOMIC_RELAXED,
                                 __HIP_MEMORY_SCOPE_AGENT);
          if ((unsigned)(pv >> 32) >= tt) { h1 = __uint_as_float((unsigned)pv); d1 = true; }
        }
        if (!d2) {
          pv = __hip_atomic_load(&hb[tid + 1024], __ATOMIC_RELAXED,
                                 __HIP_MEMORY_SCOPE_AGENT);
          if ((unsigned)(pv >> 32) >= tt) { h2 = __uint_as_float((unsigned)pv); d2 = true; }
        }
        if (!d3) {
          pv = __hip_atomic_load(&hb[tid + 1536], __ATOMIC_RELAXED,
                                 __HIP_MEMORY_SCOPE_AGENT);
          if ((unsigned)(pv >> 32) >= tt) { h3 = __uint_as_float((unsigned)pv); d3 = true; }
        }
        if (d0 & d1 & d2 & d3) break;
        if (++guard > POLL_GUARD) { alive = 0; break; }  // wedge -> bail loud
        __builtin_amdgcn_s_sleep(1);
      }
      xh[hw0] = h0;
      xh[hw1] = h1;
      xh[hw2] = h2;
      xh[hw3] = h3;
    }
    __syncthreads();   // sync1: xh fully staged (x + h)

    // [F] 192 FMAs against register-resident weights
    float ac0 = 0.f, ac1 = 0.f, ac2 = 0.f, ac3 = 0.f,
          ac4 = 0.f, ac5 = 0.f, ac6 = 0.f, ac7 = 0.f;
    {
      floatx4 v;
      FMAJ(0); FMAJ(1); FMAJ(2); FMAJ(3); FMAJ(4); FMAJ(5);
    }

    // [G] wave reduction (64 lanes -> lane 0) for the 8 row-sums
    WRED(ac0, 0); WRED(ac1, 1); WRED(ac2, 2); WRED(ac3, 3);
    WRED(ac4, 4); WRED(ac5, 5); WRED(ac6, 6); WRED(ac7, 7);
    __syncthreads();   // sync2: partials visible (also fences xh reuse)

    // [K] combine partials + gates + state update (rows by threads 0..7),
    // then publish packet (tag t+1, h) -- single 8B store, no drain needed.
    if (tid < 8) {
      const int rr = tid;
      const float pi = bl[rr]      + red[0 * 8 + rr] + red[1 * 8 + rr];
      const float pf = bl[8 + rr]  + red[2 * 8 + rr] + red[3 * 8 + rr];
      const float po = bl[16 + rr] + red[4 * 8 + rr] + red[5 * 8 + rr];
      const float pc = bl[24 + rr] + red[6 * 8 + rr] + red[7 * 8 + rr];
      const float iv = fsigmoid(pi);
      const float fv = fsigmoid(pf);
      const float ov = fsigmoid(po);
      const float ct = ftanh(pc);
      const float cn = fv * cl[rr] + iv * ct;
      cl[rr] = cn;
      const float hv = ov * ftanh(cn);
      hlast = hv;
      const unsigned long long pk =
          ((unsigned long long)(unsigned)(t + 1) << 32) |
          (unsigned long long)__float_as_uint(hv);
      __hip_atomic_store(&hcomm[(((size_t)((t + 1) & 1)) << 11) + row0 + rr],
                         pk, __ATOMIC_RELAXED, __HIP_MEMORY_SCOPE_AGENT);
    }
    // no barrier here: next iteration's xh writes are behind sync1, and
    // red[] rewrites are behind next sync1 as well (wave 0 reaches it only
    // after [K]).
  }

  if (tid < 8) {
    hbuf[row0 + tid] = hlast;
    cbuf[row0 + tid] = cl[tid];
  }
}

// ---------------------------------------------------------------------------
// out[0:512] = W2 @ [h; c] + b2   (fp32 in, fp32 out)
// ---------------------------------------------------------------------------
__global__ __launch_bounds__(256)
void final_kernel(const float* __restrict__ W2, const float* __restrict__ b2,
                  const float* __restrict__ hfin, const float* __restrict__ cfin,
                  float* __restrict__ out)
{
  const int wv   = threadIdx.x >> 6;
  const int lane = threadIdx.x & 63;
  const int row  = (blockIdx.x << 2) + wv;
  const float* wr = W2 + (size_t)row * (2 * H_DIM);
  float acc = 0.f;
#pragma unroll 4
  for (int k = lane; k < H_DIM; k += 64) {
    acc = fmaf(wr[k], hfin[k], acc);
    acc = fmaf(wr[H_DIM + k], cfin[k], acc);
  }
#pragma unroll
  for (int off = 32; off > 0; off >>= 1) acc += __shfl_down(acc, off, 64);
  if (lane == 0) out[row] = acc + b2[row];
}

__global__ __launch_bounds__(256)
void copy_h_kernel(const float* __restrict__ hfin, float* __restrict__ out)
{
  const int i = blockIdx.x * 256 + threadIdx.x;
  if (i < H_DIM) out[OUT_DIM + i] = hfin[i];
}

// ---------------------------------------------------------------------------
extern "C" void kernel_launch(void* const* d_in, const int* in_sizes, int n_in,
                              void* d_out, int out_size, void* d_ws, size_t ws_size,
                              hipStream_t stream)
{
  const float* x   = (const float*)d_in[0];
  const float* Wi  = (const float*)d_in[1];
  const float* bi  = (const float*)d_in[2];
  const float* Wf  = (const float*)d_in[3];
  const float* bff = (const float*)d_in[4];
  const float* Wo  = (const float*)d_in[5];
  const float* bo  = (const float*)d_in[6];
  const float* Wc  = (const float*)d_in[7];
  const float* bc  = (const float*)d_in[8];
  const float* W2  = (const float*)d_in[9];
  const float* b2  = (const float*)d_in[10];
  float* out = (float*)d_out;

  // workspace: [hcomm 2*H u64 = 32 KB][hbuf H f32][cbuf H f32]  (~48 KB)
  char* ws = (char*)d_ws;
  unsigned long long* hcomm = (unsigned long long*)ws;
  float* hbuf = (float*)(ws + 2 * H_DIM * sizeof(unsigned long long));
  float* cbuf = hbuf + H_DIM;

  // zeroed packets == (tag 0, h=0): the valid initial state for step 0
  hipMemsetAsync(hcomm, 0, 2 * H_DIM * sizeof(unsigned long long), stream);

  lstm_scan<<<dim3(NBLK), dim3(NTHR), 0, stream>>>(
      Wi, Wf, Wo, Wc, bi, bff, bo, bc, x, hcomm, hbuf, cbuf);
  final_kernel<<<dim3(OUT_DIM / 4), 256, 0, stream>>>(W2, b2, hbuf, cbuf, out);
  copy_h_kernel<<<dim3((H_DIM + 255) / 256), 256, 0, stream>>>(hbuf, out);
}

// Round 17
// 16722.672 us; speedup vs baseline: 1.0673x; 1.0515x over previous
//
#include <hip/hip_runtime.h>
#include <stdint.h>

#define T_STEPS 4096
#define IN_DIM  1024
#define H_DIM   2048
#define OUT_DIM 512
#define W_STRIDE 3072        // IN + H
#define NBLK    256          // one persistent block per CU
#define NTHR    512          // 8 waves/block -> VGPR cap 256 (2 waves/SIMD)
#define POLL_GUARD 65536     // bounded spin before declaring wedge

typedef __attribute__((ext_vector_type(4))) float floatx4;

// XOR swizzle on 16B granules: keeps float4 alignment, spreads bank groups.
__device__ __forceinline__ int swz(int q) { return q ^ ((q >> 3) & 7); }

__device__ __forceinline__ float fsigmoid(float v) {
  return __builtin_amdgcn_rcpf(1.f + __expf(-v));
}
__device__ __forceinline__ float ftanh(float v) {
  return 1.f - 2.f * __builtin_amdgcn_rcpf(1.f + __expf(2.f * v));
}
__device__ __forceinline__ unsigned umin2(unsigned a, unsigned b) {
  return a < b ? a : b;
}

// ---------------------------------------------------------------------------
// Persistent fused LSTM scan. Block b owns h rows [8b, 8b+8).
// 512 threads: grp = tid>>7 = gate; u = tid&127 = col-slice (24 cols).
//
// R11 change: BATCHED poll loads. The guarded per-slot poll (if(!d0){load;
// check}...) put each load in its own basic block -> s_waitcnt vmcnt(0)
// after EVERY load: 4 serialized agent-scope round trips (~2400 cyc) per
// poll iteration. That latency chain, not BW or contention (R9 null) or
// weight streaming (R10: VGPR=128 + FETCH 0.4GB refuted it -- weights sit
// in AGPRs via the unified file), is the theory for the 10.3k-cycle step.
// Now: load all 4 packets unconditionally (relaxed -> no inter-load order,
// ONE waitcnt), exit when min(tag) >= t. Monotone-safe: slots in buffer
// (t&1) hold only tag t-2 or t while we poll (producer can't write t+2
// before we publish t+1), so the exiting iteration's values are valid.
//
// Handshake (measured 29.1->17.8ms): single-hop 8B (tag<<32|float) packet,
// relaxed agent-scope store; ping-pong on t&1; bounded bailout so stale-
// state replay surfaces as a wrong answer, not a hung container.
// ---------------------------------------------------------------------------
#define WDECL(r) floatx4 w##r##_0, w##r##_1, w##r##_2, w##r##_3, w##r##_4, w##r##_5
#define WLOAD(r) do { const float* rp_ = wbase + (size_t)(r) * W_STRIDE;      \
    w##r##_0 = *(const floatx4*)(rp_ +  0);                                   \
    w##r##_1 = *(const floatx4*)(rp_ +  4);                                   \
    w##r##_2 = *(const floatx4*)(rp_ +  8);                                   \
    w##r##_3 = *(const floatx4*)(rp_ + 12);                                   \
    w##r##_4 = *(const floatx4*)(rp_ + 16);                                   \
    w##r##_5 = *(const floatx4*)(rp_ + 20); } while (0)
#define WPIN(r) asm volatile("" : "+v"(w##r##_0), "+v"(w##r##_1),             \
    "+v"(w##r##_2), "+v"(w##r##_3), "+v"(w##r##_4), "+v"(w##r##_5))
#define FMA4(acc, wq) do {                                                    \
    acc = fmaf(wq.x, v.x, acc); acc = fmaf(wq.y, v.y, acc);                   \
    acc = fmaf(wq.z, v.z, acc); acc = fmaf(wq.w, v.w, acc); } while (0)
#define FMAJ(j) do { v = *(const floatx4*)(xh + a_v##j);                      \
    FMA4(ac0, w0_##j); FMA4(ac1, w1_##j); FMA4(ac2, w2_##j);                  \
    FMA4(ac3, w3_##j); FMA4(ac4, w4_##j); FMA4(ac5, w5_##j);                  \
    FMA4(ac6, w6_##j); FMA4(ac7, w7_##j); } while (0)
#define WRED(acc, r) do { float a_ = acc;                                     \
    a_ += __shfl_down(a_, 32, 64); a_ += __shfl_down(a_, 16, 64);             \
    a_ += __shfl_down(a_, 8, 64);  a_ += __shfl_down(a_, 4, 64);              \
    a_ += __shfl_down(a_, 2, 64);  a_ += __shfl_down(a_, 1, 64);              \
    if (lane == 0) red[wv * 8 + (r)] = a_; } while (0)

__global__ __launch_bounds__(NTHR, 2)
void lstm_scan(const float* __restrict__ Wi, const float* __restrict__ Wf,
               const float* __restrict__ Wo, const float* __restrict__ Wc,
               const float* __restrict__ bi, const float* __restrict__ bff,
               const float* __restrict__ bo, const float* __restrict__ bc,
               const float* __restrict__ x,
               unsigned long long* __restrict__ hcomm,  // [2][H_DIM] packets
               float* __restrict__ hbuf,                // [H_DIM] final h
               float* __restrict__ cbuf)                // [H_DIM] final c
{
  __shared__ float xh[768 * 4];   // concat(x,h) in XOR-swizzled 16B granules
  __shared__ float red[8 * 8];    // per-wave partials (8 waves x 8 rows)
  __shared__ float bl[32];        // biases (gate*8+row)
  __shared__ float cl[8];         // cell state for this block's rows

  const int tid  = threadIdx.x;
  const int b    = blockIdx.x;
  const int row0 = b << 3;
  const int grp  = tid >> 7;      // gate id 0..3
  const int u    = tid & 127;     // column slice: cols [24u, 24u+24)
  const int wv   = tid >> 6;      // wave id 0..7
  const int lane = tid & 63;

  const float* Wsel = (grp == 0) ? Wi : (grp == 1) ? Wf : (grp == 2) ? Wo : Wc;
  const float* wbase = Wsel + (size_t)row0 * W_STRIDE + 24 * u;

  WDECL(0); WDECL(1); WDECL(2); WDECL(3);
  WDECL(4); WDECL(5); WDECL(6); WDECL(7);
  WLOAD(0); WLOAD(1); WLOAD(2); WLOAD(3);
  WLOAD(4); WLOAD(5); WLOAD(6); WLOAD(7);
  WPIN(0); WPIN(1); WPIN(2); WPIN(3);
  WPIN(4); WPIN(5); WPIN(6); WPIN(7);

  if (tid < 32) {
    const float* Bsel = (tid < 8) ? bi : (tid < 16) ? bff : (tid < 24) ? bo : bc;
    bl[tid] = Bsel[row0 + (tid & 7)];
  }
  if (tid < 8) cl[tid] = 0.f;
  __syncthreads();

  // loop-invariant LDS addresses (dword units)
  const int a_v0 = swz(6 * u + 0) << 2;
  const int a_v1 = swz(6 * u + 1) << 2;
  const int a_v2 = swz(6 * u + 2) << 2;
  const int a_v3 = swz(6 * u + 3) << 2;
  const int a_v4 = swz(6 * u + 4) << 2;
  const int a_v5 = swz(6 * u + 5) << 2;
  const int hw0 = (swz(256 + (tid >> 2) +   0) << 2) + (tid & 3);
  const int hw1 = (swz(256 + (tid >> 2) + 128) << 2) + (tid & 3);
  const int hw2 = (swz(256 + (tid >> 2) + 256) << 2) + (tid & 3);
  const int hw3 = (swz(256 + (tid >> 2) + 384) << 2) + (tid & 3);

  float hlast = 0.f;
  int   alive = 1;   // cleared if a poll ever exhausts POLL_GUARD

  for (int t = 0; t < T_STEPS; ++t) {
    // [A] stage x[t] (granules 0..255); issue early so the global load
    // latency hides under the h poll below.
    if (tid >= 256) {
      const int q = tid - 256;
      const floatx4 xv = *(const floatx4*)(x + ((size_t)t << 10) + (q << 2));
      *(floatx4*)(xh + (swz(q) << 2)) = xv;
    }

    // [B+D fused] BATCHED poll: 4 unconditional independent loads per
    // iteration (-> one waitcnt), exit when min(tag) >= t.
    {
      unsigned long long* hb = hcomm + ((size_t)(t & 1) << 11);
      const unsigned tt = (unsigned)t;
      unsigned long long p0 = 0, p1 = 0, p2 = 0, p3 = 0;
      int guard = 0;
      while (alive) {
        p0 = __hip_atomic_load(&hb[tid], __ATOMIC_RELAXED,
                               __HIP_MEMORY_SCOPE_AGENT);
        p1 = __hip_atomic_load(&hb[tid + 512], __ATOMIC_RELAXED,
                               __HIP_MEMORY_SCOPE_AGENT);
        p2 = __hip_atomic_load(&hb[tid + 1024], __ATOMIC_RELAXED,
                               __HIP_MEMORY_SCOPE_AGENT);
        p3 = __hip_atomic_load(&hb[tid + 1536], __ATOMIC_RELAXED,
                               __HIP_MEMORY_SCOPE_AGENT);
        const unsigned mn = umin2(umin2((unsigned)(p0 >> 32),
                                        (unsigned)(p1 >> 32)),
                                  umin2((unsigned)(p2 >> 32),
                                        (unsigned)(p3 >> 32)));
        if (mn >= tt) break;
        if (++guard > POLL_GUARD) { alive = 0; break; }  // wedge -> bail loud
        __builtin_amdgcn_s_sleep(1);
      }
      xh[hw0] = __uint_as_float((unsigned)p0);
      xh[hw1] = __uint_as_float((unsigned)p1);
      xh[hw2] = __uint_as_float((unsigned)p2);
      xh[hw3] = __uint_as_float((unsigned)p3);
    }
    __syncthreads();   // sync1: xh fully staged (x + h)

    // [F] 192 FMAs against register-resident weights
    float ac0 = 0.f, ac1 = 0.f, ac2 = 0.f, ac3 = 0.f,
          ac4 = 0.f, ac5 = 0.f, ac6 = 0.f, ac7 = 0.f;
    {
      floatx4 v;
      FMAJ(0); FMAJ(1); FMAJ(2); FMAJ(3); FMAJ(4); FMAJ(5);
    }

    // [G] wave reduction (64 lanes -> lane 0) for the 8 row-sums
    WRED(ac0, 0); WRED(ac1, 1); WRED(ac2, 2); WRED(ac3, 3);
    WRED(ac4, 4); WRED(ac5, 5); WRED(ac6, 6); WRED(ac7, 7);
    __syncthreads();   // sync2: partials visible (also fences xh reuse)

    // [K] combine partials + gates + state update (rows by threads 0..7),
    // then publish packet (tag t+1, h) -- single 8B store, no drain needed.
    if (tid < 8) {
      const int rr = tid;
      const float pi = bl[rr]      + red[0 * 8 + rr] + red[1 * 8 + rr];
      const float pf = bl[8 + rr]  + red[2 * 8 + rr] + red[3 * 8 + rr];
      const float po = bl[16 + rr] + red[4 * 8 + rr] + red[5 * 8 + rr];
      const float pc = bl[24 + rr] + red[6 * 8 + rr] + red[7 * 8 + rr];
      const float iv = fsigmoid(pi);
      const float fv = fsigmoid(pf);
      const float ov = fsigmoid(po);
      const float ct = ftanh(pc);
      const float cn = fv * cl[rr] + iv * ct;
      cl[rr] = cn;
      const float hv = ov * ftanh(cn);
      hlast = hv;
      const unsigned long long pk =
          ((unsigned long long)(unsigned)(t + 1) << 32) |
          (unsigned long long)__float_as_uint(hv);
      __hip_atomic_store(&hcomm[(((size_t)((t + 1) & 1)) << 11) + row0 + rr],
                         pk, __ATOMIC_RELAXED, __HIP_MEMORY_SCOPE_AGENT);
    }
    // no barrier here: next iteration's xh writes are behind sync1, and
    // red[] rewrites are behind next sync1 as well (wave 0 reaches it only
    // after [K]).
  }

  if (tid < 8) {
    hbuf[row0 + tid] = hlast;
    cbuf[row0 + tid] = cl[tid];
  }
}

// ---------------------------------------------------------------------------
// out[0:512] = W2 @ [h; c] + b2   (fp32 in, fp32 out)
// ---------------------------------------------------------------------------
__global__ __launch_bounds__(256)
void final_kernel(const float* __restrict__ W2, const float* __restrict__ b2,
                  const float* __restrict__ hfin, const float* __restrict__ cfin,
                  float* __restrict__ out)
{
  const int wv   = threadIdx.x >> 6;
  const int lane = threadIdx.x & 63;
  const int row  = (blockIdx.x << 2) + wv;
  const float* wr = W2 + (size_t)row * (2 * H_DIM);
  float acc = 0.f;
#pragma unroll 4
  for (int k = lane; k < H_DIM; k += 64) {
    acc = fmaf(wr[k], hfin[k], acc);
    acc = fmaf(wr[H_DIM + k], cfin[k], acc);
  }
#pragma unroll
  for (int off = 32; off > 0; off >>= 1) acc += __shfl_down(acc, off, 64);
  if (lane == 0) out[row] = acc + b2[row];
}

__global__ __launch_bounds__(256)
void copy_h_kernel(const float* __restrict__ hfin, float* __restrict__ out)
{
  const int i = blockIdx.x * 256 + threadIdx.x;
  if (i < H_DIM) out[OUT_DIM + i] = hfin[i];
}

// ---------------------------------------------------------------------------
extern "C" void kernel_launch(void* const* d_in, const int* in_sizes, int n_in,
                              void* d_out, int out_size, void* d_ws, size_t ws_size,
                              hipStream_t stream)
{
  const float* x   = (const float*)d_in[0];
  const float* Wi  = (const float*)d_in[1];
  const float* bi  = (const float*)d_in[2];
  const float* Wf  = (const float*)d_in[3];
  const float* bff = (const float*)d_in[4];
  const float* Wo  = (const float*)d_in[5];
  const float* bo  = (const float*)d_in[6];
  const float* Wc  = (const float*)d_in[7];
  const float* bc  = (const float*)d_in[8];
  const float* W2  = (const float*)d_in[9];
  const float* b2  = (const float*)d_in[10];
  float* out = (float*)d_out;

  // workspace: [hcomm 2*H u64 = 32 KB][hbuf H f32][cbuf H f32]  (~48 KB)
  char* ws = (char*)d_ws;
  unsigned long long* hcomm = (unsigned long long*)ws;
  float* hbuf = (float*)(ws + 2 * H_DIM * sizeof(unsigned long long));
  float* cbuf = hbuf + H_DIM;

  // zeroed packets == (tag 0, h=0): the valid initial state for step 0
  hipMemsetAsync(hcomm, 0, 2 * H_DIM * sizeof(unsigned long long), stream);

  lstm_scan<<<dim3(NBLK), dim3(NTHR), 0, stream>>>(
      Wi, Wf, Wo, Wc, bi, bff, bo, bc, x, hcomm, hbuf, cbuf);
  final_kernel<<<dim3(OUT_DIM / 4), 256, 0, stream>>>(W2, b2, hbuf, cbuf, out);
  copy_h_kernel<<<dim3((H_DIM + 255) / 256), 256, 0, stream>>>(hbuf, out);
}

// Round 19
// 16616.512 us; speedup vs baseline: 1.0742x; 1.0064x over previous
//
#include <hip/hip_runtime.h>
#include <stdint.h>

#define T_STEPS 4096
#define IN_DIM  1024
#define H_DIM   2048
#define OUT_DIM 512
#define W_STRIDE 3072        // IN + H
#define NBLK    256          // one persistent block per CU
#define NTHR    512          // 8 waves/block -> VGPR cap 256 (2 waves/SIMD)
#define POLL_GUARD 65536     // bounded spin before declaring wedge

typedef __attribute__((ext_vector_type(4))) float floatx4;

// XOR swizzle on 16B granules: keeps float4 alignment, spreads bank groups.
__device__ __forceinline__ int swz(int q) { return q ^ ((q >> 3) & 7); }

__device__ __forceinline__ float fsigmoid(float v) {
  return __builtin_amdgcn_rcpf(1.f + __expf(-v));
}
__device__ __forceinline__ float ftanh(float v) {
  return 1.f - 2.f * __builtin_amdgcn_rcpf(1.f + __expf(2.f * v));
}
__device__ __forceinline__ unsigned umin2(unsigned a, unsigned b) {
  return a < b ? a : b;
}

// ---------------------------------------------------------------------------
// Persistent fused LSTM scan. Block b owns h rows [8b, 8b+8).
// 512 threads: grp = tid>>7 = gate; u = tid&127.
//
// R12 change: X-PART OVERLAP. R11's batched poll gave only -4.9% (pred
// -18..-37%): the poll iteration is load-latency-bound, so intra-iteration
// serialization wasn't the sink. Remaining attackable term = the post-
// detect serial tail (stage+sync+192 FMA+reduce+[K] ~ 1400cy). One third
// of the FMAs (x-cols) don't depend on h_t. Re-slice each thread to
// 8 x-cols [8u,8u+8) + 16 h-cols [1024+16u,+16) (same 192 weight regs).
// Per step: load 8 x to regs (L1-resident), issue poll loads, x-FMA while
// polls fly, then detect -> stage h -> sync -> 128 h-FMAs. Also removes
// the x LDS staging phase and cuts LDS reads 48->32 KB/step.
// Falsified so far: contention (R9 8x-replication null), MALL weight
// streaming (R10 VGPR=128 + FETCH 0.4GB -> weights in AGPRs), intra-poll
// serialization (R11, -4.9% only).
//
// Handshake (29.1->17.8->16.7ms): single-hop 8B (tag<<32|float) packet,
// relaxed agent-scope store; poll exits on min(tag)>=t (monotone-safe:
// polled slots hold only t-2 or t). Ping-pong on t&1. Bounded bailout so
// stale-state replay surfaces as a wrong answer, not a hung container.
// ---------------------------------------------------------------------------
#define FMA4(acc, wq, v) do {                                                 \
    acc = fmaf(wq.x, v.x, acc); acc = fmaf(wq.y, v.y, acc);                   \
    acc = fmaf(wq.z, v.z, acc); acc = fmaf(wq.w, v.w, acc); } while (0)
#define WDECL(r) floatx4 wx##r##_0, wx##r##_1,                                \
    wh##r##_0, wh##r##_1, wh##r##_2, wh##r##_3
#define WLOAD(r) do {                                                         \
    const float* rx_ = wxb + (size_t)(r) * W_STRIDE;                          \
    const float* rh_ = whb + (size_t)(r) * W_STRIDE;                          \
    wx##r##_0 = *(const floatx4*)(rx_ + 0);                                   \
    wx##r##_1 = *(const floatx4*)(rx_ + 4);                                   \
    wh##r##_0 = *(const floatx4*)(rh_ + 0);                                   \
    wh##r##_1 = *(const floatx4*)(rh_ + 4);                                   \
    wh##r##_2 = *(const floatx4*)(rh_ + 8);                                   \
    wh##r##_3 = *(const floatx4*)(rh_ + 12); } while (0)
#define WPIN(r) asm volatile("" : "+v"(wx##r##_0), "+v"(wx##r##_1),           \
    "+v"(wh##r##_0), "+v"(wh##r##_1), "+v"(wh##r##_2), "+v"(wh##r##_3))
#define XFMA(r) do { FMA4(ac##r, wx##r##_0, xa);                              \
    FMA4(ac##r, wx##r##_1, xb); } while (0)
#define HFMAK(k) do {                                                         \
    const floatx4 v = *(const floatx4*)(hl + a_h##k);                         \
    FMA4(ac0, wh0_##k, v); FMA4(ac1, wh1_##k, v);                             \
    FMA4(ac2, wh2_##k, v); FMA4(ac3, wh3_##k, v);                             \
    FMA4(ac4, wh4_##k, v); FMA4(ac5, wh5_##k, v);                             \
    FMA4(ac6, wh6_##k, v); FMA4(ac7, wh7_##k, v); } while (0)
#define WRED(acc, r) do { float a_ = acc;                                     \
    a_ += __shfl_down(a_, 32, 64); a_ += __shfl_down(a_, 16, 64);             \
    a_ += __shfl_down(a_, 8, 64);  a_ += __shfl_down(a_, 4, 64);              \
    a_ += __shfl_down(a_, 2, 64);  a_ += __shfl_down(a_, 1, 64);              \
    if (lane == 0) red[wv * 8 + (r)] = a_; } while (0)

__global__ __launch_bounds__(NTHR, 2)
void lstm_scan(const float* __restrict__ Wi, const float* __restrict__ Wf,
               const float* __restrict__ Wo, const float* __restrict__ Wc,
               const float* __restrict__ bi, const float* __restrict__ bff,
               const float* __restrict__ bo, const float* __restrict__ bc,
               const float* __restrict__ x,
               unsigned long long* __restrict__ hcomm,  // [2][H_DIM] packets
               float* __restrict__ hbuf,                // [H_DIM] final h
               float* __restrict__ cbuf)                // [H_DIM] final c
{
  __shared__ float hl[512 * 4];   // h_t in XOR-swizzled 16B granules (8 KB)
  __shared__ float red[8 * 8];    // per-wave partials (8 waves x 8 rows)
  __shared__ float bl[32];        // biases (gate*8+row)
  __shared__ float cl[8];         // cell state for this block's rows

  const int tid  = threadIdx.x;
  const int b    = blockIdx.x;
  const int row0 = b << 3;
  const int grp  = tid >> 7;      // gate id 0..3
  const int u    = tid & 127;     // col slice: x [8u,8u+8), h [16u,16u+16)
  const int wv   = tid >> 6;      // wave id 0..7
  const int lane = tid & 63;

  const float* Wsel = (grp == 0) ? Wi : (grp == 1) ? Wf : (grp == 2) ? Wo : Wc;
  const float* wxb = Wsel + (size_t)row0 * W_STRIDE + (u << 3);
  const float* whb = Wsel + (size_t)row0 * W_STRIDE + IN_DIM + (u << 4);

  WDECL(0); WDECL(1); WDECL(2); WDECL(3);
  WDECL(4); WDECL(5); WDECL(6); WDECL(7);
  WLOAD(0); WLOAD(1); WLOAD(2); WLOAD(3);
  WLOAD(4); WLOAD(5); WLOAD(6); WLOAD(7);
  WPIN(0); WPIN(1); WPIN(2); WPIN(3);
  WPIN(4); WPIN(5); WPIN(6); WPIN(7);

  if (tid < 32) {
    const float* Bsel = (tid < 8) ? bi : (tid < 16) ? bff : (tid < 24) ? bo : bc;
    bl[tid] = Bsel[row0 + (tid & 7)];
  }
  if (tid < 8) cl[tid] = 0.f;
  __syncthreads();

  // loop-invariant LDS addresses (dword units), h-only granule space [0,512)
  const int a_h0 = swz(4 * u + 0) << 2;
  const int a_h1 = swz(4 * u + 1) << 2;
  const int a_h2 = swz(4 * u + 2) << 2;
  const int a_h3 = swz(4 * u + 3) << 2;
  const int hv0 = (swz((tid >> 2) +   0) << 2) + (tid & 3);
  const int hv1 = (swz((tid >> 2) + 128) << 2) + (tid & 3);
  const int hv2 = (swz((tid >> 2) + 256) << 2) + (tid & 3);
  const int hv3 = (swz((tid >> 2) + 384) << 2) + (tid & 3);

  float hlast = 0.f;
  int   alive = 1;   // cleared if a poll ever exhausts POLL_GUARD

  for (int t = 0; t < T_STEPS; ++t) {
    // [X] per-thread x loads (L1-resident row) -- issue before poll loads
    const float* xp = x + ((size_t)t << 10) + (u << 3);
    const floatx4 xa = *(const floatx4*)(xp);
    const floatx4 xb = *(const floatx4*)(xp + 4);

    // [P] first poll issue (4 independent relaxed loads, in flight during
    // the x-FMA below)
    unsigned long long* hb = hcomm + ((size_t)(t & 1) << 11);
    const unsigned tt = (unsigned)t;
    unsigned long long p0, p1, p2, p3;
    p0 = __hip_atomic_load(&hb[tid], __ATOMIC_RELAXED,
                           __HIP_MEMORY_SCOPE_AGENT);
    p1 = __hip_atomic_load(&hb[tid + 512], __ATOMIC_RELAXED,
                           __HIP_MEMORY_SCOPE_AGENT);
    p2 = __hip_atomic_load(&hb[tid + 1024], __ATOMIC_RELAXED,
                           __HIP_MEMORY_SCOPE_AGENT);
    p3 = __hip_atomic_load(&hb[tid + 1536], __ATOMIC_RELAXED,
                           __HIP_MEMORY_SCOPE_AGENT);

    // [F-x] 64 FMAs that don't depend on h_t -- overlap the poll flight
    float ac0 = 0.f, ac1 = 0.f, ac2 = 0.f, ac3 = 0.f,
          ac4 = 0.f, ac5 = 0.f, ac6 = 0.f, ac7 = 0.f;
    XFMA(0); XFMA(1); XFMA(2); XFMA(3);
    XFMA(4); XFMA(5); XFMA(6); XFMA(7);

    // [B] tag check + batched re-poll (R11 structure)
    {
      unsigned mn = umin2(umin2((unsigned)(p0 >> 32), (unsigned)(p1 >> 32)),
                          umin2((unsigned)(p2 >> 32), (unsigned)(p3 >> 32)));
      int guard = 0;
      while (alive && mn < tt) {
        if (++guard > POLL_GUARD) { alive = 0; break; }  // wedge -> bail loud
        __builtin_amdgcn_s_sleep(1);
        p0 = __hip_atomic_load(&hb[tid], __ATOMIC_RELAXED,
                               __HIP_MEMORY_SCOPE_AGENT);
        p1 = __hip_atomic_load(&hb[tid + 512], __ATOMIC_RELAXED,
                               __HIP_MEMORY_SCOPE_AGENT);
        p2 = __hip_atomic_load(&hb[tid + 1024], __ATOMIC_RELAXED,
                               __HIP_MEMORY_SCOPE_AGENT);
        p3 = __hip_atomic_load(&hb[tid + 1536], __ATOMIC_RELAXED,
                               __HIP_MEMORY_SCOPE_AGENT);
        mn = umin2(umin2((unsigned)(p0 >> 32), (unsigned)(p1 >> 32)),
                   umin2((unsigned)(p2 >> 32), (unsigned)(p3 >> 32)));
      }
    }
    // [D] stage the 4 polled h values to LDS (swizzled granules)
    hl[hv0] = __uint_as_float((unsigned)p0);
    hl[hv1] = __uint_as_float((unsigned)p1);
    hl[hv2] = __uint_as_float((unsigned)p2);
    hl[hv3] = __uint_as_float((unsigned)p3);
    __syncthreads();   // sync1: h fully staged

    // [F-h] 128 FMAs against register-resident h-weights
    HFMAK(0); HFMAK(1); HFMAK(2); HFMAK(3);

    // [G] wave reduction (64 lanes -> lane 0) for the 8 row-sums
    WRED(ac0, 0); WRED(ac1, 1); WRED(ac2, 2); WRED(ac3, 3);
    WRED(ac4, 4); WRED(ac5, 5); WRED(ac6, 6); WRED(ac7, 7);
    __syncthreads();   // sync2: partials visible (also fences hl reuse)

    // [K] combine partials + gates + state update (rows by threads 0..7),
    // then publish packet (tag t+1, h) -- single 8B store, no drain needed.
    if (tid < 8) {
      const int rr = tid;
      const float pi = bl[rr]      + red[0 * 8 + rr] + red[1 * 8 + rr];
      const float pf = bl[8 + rr]  + red[2 * 8 + rr] + red[3 * 8 + rr];
      const float po = bl[16 + rr] + red[4 * 8 + rr] + red[5 * 8 + rr];
      const float pc = bl[24 + rr] + red[6 * 8 + rr] + red[7 * 8 + rr];
      const float iv = fsigmoid(pi);
      const float fv = fsigmoid(pf);
      const float ov = fsigmoid(po);
      const float ct = ftanh(pc);
      const float cn = fv * cl[rr] + iv * ct;
      cl[rr] = cn;
      const float hv = ov * ftanh(cn);
      hlast = hv;
      const unsigned long long pk =
          ((unsigned long long)(unsigned)(t + 1) << 32) |
          (unsigned long long)__float_as_uint(hv);
      __hip_atomic_store(&hcomm[(((size_t)((t + 1) & 1)) << 11) + row0 + rr],
                         pk, __ATOMIC_RELAXED, __HIP_MEMORY_SCOPE_AGENT);
    }
    // no barrier here: next step's hl writes are behind sync1, and red[]
    // rewrites are behind next sync1 as well (wave 0 reaches it after [K]).
  }

  if (tid < 8) {
    hbuf[row0 + tid] = hlast;
    cbuf[row0 + tid] = cl[tid];
  }
}

// ---------------------------------------------------------------------------
// out[0:512] = W2 @ [h; c] + b2   (fp32 in, fp32 out)
// ---------------------------------------------------------------------------
__global__ __launch_bounds__(256)
void final_kernel(const float* __restrict__ W2, const float* __restrict__ b2,
                  const float* __restrict__ hfin, const float* __restrict__ cfin,
                  float* __restrict__ out)
{
  const int wv   = threadIdx.x >> 6;
  const int lane = threadIdx.x & 63;
  const int row  = (blockIdx.x << 2) + wv;
  const float* wr = W2 + (size_t)row * (2 * H_DIM);
  float acc = 0.f;
#pragma unroll 4
  for (int k = lane; k < H_DIM; k += 64) {
    acc = fmaf(wr[k], hfin[k], acc);
    acc = fmaf(wr[H_DIM + k], cfin[k], acc);
  }
#pragma unroll
  for (int off = 32; off > 0; off >>= 1) acc += __shfl_down(acc, off, 64);
  if (lane == 0) out[row] = acc + b2[row];
}

__global__ __launch_bounds__(256)
void copy_h_kernel(const float* __restrict__ hfin, float* __restrict__ out)
{
  const int i = blockIdx.x * 256 + threadIdx.x;
  if (i < H_DIM) out[OUT_DIM + i] = hfin[i];
}

// ---------------------------------------------------------------------------
extern "C" void kernel_launch(void* const* d_in, const int* in_sizes, int n_in,
                              void* d_out, int out_size, void* d_ws, size_t ws_size,
                              hipStream_t stream)
{
  const float* x   = (const float*)d_in[0];
  const float* Wi  = (const float*)d_in[1];
  const float* bi  = (const float*)d_in[2];
  const float* Wf  = (const float*)d_in[3];
  const float* bff = (const float*)d_in[4];
  const float* Wo  = (const float*)d_in[5];
  const float* bo  = (const float*)d_in[6];
  const float* Wc  = (const float*)d_in[7];
  const float* bc  = (const float*)d_in[8];
  const float* W2  = (const float*)d_in[9];
  const float* b2  = (const float*)d_in[10];
  float* out = (float*)d_out;

  // workspace: [hcomm 2*H u64 = 32 KB][hbuf H f32][cbuf H f32]  (~48 KB)
  char* ws = (char*)d_ws;
  unsigned long long* hcomm = (unsigned long long*)ws;
  float* hbuf = (float*)(ws + 2 * H_DIM * sizeof(unsigned long long));
  float* cbuf = hbuf + H_DIM;

  // zeroed packets == (tag 0, h=0): the valid initial state for step 0
  hipMemsetAsync(hcomm, 0, 2 * H_DIM * sizeof(unsigned long long), stream);

  lstm_scan<<<dim3(NBLK), dim3(NTHR), 0, stream>>>(
      Wi, Wf, Wo, Wc, bi, bff, bo, bc, x, hcomm, hbuf, cbuf);
  final_kernel<<<dim3(OUT_DIM / 4), 256, 0, stream>>>(W2, b2, hbuf, cbuf, out);
  copy_h_kernel<<<dim3((H_DIM + 255) / 256), 256, 0, stream>>>(hbuf, out);
}